// Round 8
// baseline (1091.730 us; speedup 1.0000x reference)
//
#include <hip/hip_runtime.h>

#define NDET 4096
#define NMEM 8192
#define DEMB 256
#define CAP  64
#define POOL 6144
#define PITCH 133

static __device__ __forceinline__ float sim_val(float f, float rm, float rsi,
                                                float cm, float csi, bool same) {
  if (!same) return 0.0f;
  return 0.5f * (expf(f - rm) * rsi + expf(f - cm) * csi);
}

// ---------- 1. fused: stable rank sort + ccnt zero + gather ----------
__global__ __launch_bounds__(256) void k_prep(const float* __restrict__ scores,
                                              const int* __restrict__ cls,
                                              const float* __restrict__ det,
                                              const float* __restrict__ emb,
                                              int* order, float* sscore, int* scls,
                                              float* sboxes, int* ccnt, float* A) {
  __shared__ float s[NDET];
  __shared__ int rank_s[256];
  int tid = threadIdx.x;
  for (int i = tid; i < NDET; i += 256) s[i] = scores[i];
  __syncthreads();
  int i = blockIdx.x * 256 + tid;
  ccnt[i] = 0;
  float si = s[i];
  int rank = 0;
  for (int j = 0; j < NDET; ++j) {
    float sj = s[j];
    rank += (sj > si) || (sj == si && j < i);
  }
  order[rank] = i;
  sscore[rank] = si;
  scls[rank] = cls[i];
  ((float4*)sboxes)[rank] = ((const float4*)det)[i];
  rank_s[tid] = rank;
  __syncthreads();
  // cooperative gather: 4 groups of 64 lanes; each row = 64 float4
  int grp = tid >> 6, lane = tid & 63;
  for (int k = grp; k < 256; k += 4) {
    int src = blockIdx.x * 256 + k;
    int dst = rank_s[k];
    ((float4*)A)[(size_t)dst * 64 + lane] =
        ((const float4*)emb)[(size_t)src * 64 + lane];
  }
}

// ---------- 2. NMS validity (all j < i suppress, as in source) ----------
__global__ __launch_bounds__(256) void k_valid(const float* __restrict__ sbox,
                                               const float* __restrict__ sscore,
                                               int* svalid) {
  int i = blockIdx.x, tid = threadIdx.x;
  float4 bi = ((const float4*)sbox)[i];
  float thr = (sscore[i] < 0.3f) ? 0.3f : 0.7f;
  float ai = fmaxf(bi.z - bi.x, 0.f) * fmaxf(bi.w - bi.y, 0.f);
  __shared__ int flag;
  if (tid == 0) flag = 0;
  __syncthreads();
  int any = 0;
  for (int j = tid; j < i; j += 256) {
    float4 bj = ((const float4*)sbox)[j];
    float aj = fmaxf(bj.z - bj.x, 0.f) * fmaxf(bj.w - bj.y, 0.f);
    float lx = fmaxf(bi.x, bj.x), ly = fmaxf(bi.y, bj.y);
    float rx = fminf(bi.z, bj.z), ry = fminf(bi.w, bj.w);
    float w = fmaxf(rx - lx, 0.f), h = fmaxf(ry - ly, 0.f);
    float inter = w * h;
    float den = fmaxf(ai + aj - inter, 1e-6f);
    any |= ((inter / den) > thr);
  }
  if (any) atomicOr(&flag, 1);
  __syncthreads();
  if (tid == 0) svalid[i] = flag ? 0 : 1;
}

#define FMA8(U, AS)                                     \
  acc[U][0] = __builtin_fmaf(AS, b0.x, acc[U][0]);      \
  acc[U][1] = __builtin_fmaf(AS, b0.y, acc[U][1]);      \
  acc[U][2] = __builtin_fmaf(AS, b0.z, acc[U][2]);      \
  acc[U][3] = __builtin_fmaf(AS, b0.w, acc[U][3]);      \
  acc[U][4] = __builtin_fmaf(AS, b1.x, acc[U][4]);      \
  acc[U][5] = __builtin_fmaf(AS, b1.y, acc[U][5]);      \
  acc[U][6] = __builtin_fmaf(AS, b1.z, acc[U][6]);      \
  acc[U][7] = __builtin_fmaf(AS, b1.w, acc[U][7]);

// ---------- 3. GEMM (feats into d_out sims region) + tile stats ----------
// PITCH=133: staging-write banks (20b+5i+a)%32 -> ~2-way (was 4-way at 132).
__global__ __launch_bounds__(256, 4) void k_gemm1(const float* __restrict__ A,
                                                  const float* __restrict__ B,
                                                  const int* __restrict__ svalid,
                                                  float2* __restrict__ rowpart,
                                                  float2* __restrict__ colpart,
                                                  float* __restrict__ feats) {
  __shared__ float smraw[2 * 32 * PITCH];  // 34048 B
  float (*As)[PITCH] = (float (*)[PITCH])smraw;
  float (*Bs)[PITCH] = (float (*)[PITCH])(smraw + 32 * PITCH);
  float (*red)[17] = (float (*)[17])smraw;  // epilogue alias
  float* tmax = smraw + 128 * 17;           // epilogue alias
  __shared__ unsigned char vrow[128];
  const int tid = threadIdx.x;
  const int tx = tid & 15, ty = tid >> 4;
  const int j0 = blockIdx.x * 128, i0 = blockIdx.y * 128;
  if (tid < 128) vrow[tid] = (unsigned char)svalid[i0 + tid];
  float acc[8][8];
#pragma unroll
  for (int u = 0; u < 8; ++u)
#pragma unroll
    for (int v = 0; v < 8; ++v) acc[u][v] = 0.f;

  for (int kt = 0; kt < DEMB / 32; ++kt) {
    const int k0 = kt * 32;
    float4 av[4], bv[4];
    int rr[4], cc[4];
#pragma unroll
    for (int e = 0; e < 4; ++e) {
      int f = e * 256 + tid;
      rr[e] = f >> 3;
      cc[e] = (f & 7) << 2;
      av[e] = *(const float4*)(A + (size_t)(i0 + rr[e]) * DEMB + k0 + cc[e]);
      bv[e] = *(const float4*)(B + (size_t)(j0 + rr[e]) * DEMB + k0 + cc[e]);
    }
    __syncthreads();
#pragma unroll
    for (int e = 0; e < 4; ++e) {
      As[cc[e] + 0][rr[e]] = av[e].x;
      As[cc[e] + 1][rr[e]] = av[e].y;
      As[cc[e] + 2][rr[e]] = av[e].z;
      As[cc[e] + 3][rr[e]] = av[e].w;
      Bs[cc[e] + 0][rr[e]] = bv[e].x;
      Bs[cc[e] + 1][rr[e]] = bv[e].y;
      Bs[cc[e] + 2][rr[e]] = bv[e].z;
      Bs[cc[e] + 3][rr[e]] = bv[e].w;
    }
    __syncthreads();
#pragma unroll
    for (int kk = 0; kk < 32; ++kk) {
      float4 a0 = *(const float4*)&As[kk][ty * 8];
      float4 a1 = *(const float4*)&As[kk][ty * 8 + 4];
      float4 b0 = *(const float4*)&Bs[kk][tx * 8];
      float4 b1 = *(const float4*)&Bs[kk][tx * 8 + 4];
      FMA8(0, a0.x) FMA8(1, a0.y) FMA8(2, a0.z) FMA8(3, a0.w)
      FMA8(4, a1.x) FMA8(5, a1.y) FMA8(6, a1.z) FMA8(7, a1.w)
    }
  }
  // ---- store raw feats (fp32) into the sims output region ----
#pragma unroll
  for (int u = 0; u < 8; ++u) {
    int row = i0 + ty * 8 + u;
    float4 o0 = {acc[u][0], acc[u][1], acc[u][2], acc[u][3]};
    float4 o1 = {acc[u][4], acc[u][5], acc[u][6], acc[u][7]};
    *(float4*)(feats + (size_t)row * NMEM + j0 + tx * 8) = o0;
    *(float4*)(feats + (size_t)row * NMEM + j0 + tx * 8 + 4) = o1;
  }
  __syncthreads();  // K-loop LDS dead; epilogue aliases it now
  // ---- row stats: exact max-then-sum within tile ----
#pragma unroll
  for (int u = 0; u < 8; ++u) {
    float m = acc[u][0];
#pragma unroll
    for (int v = 1; v < 8; ++v) m = fmaxf(m, acc[u][v]);
    red[ty * 8 + u][tx] = m;
  }
  __syncthreads();
  if (tid < 128) {
    float m = red[tid][0];
#pragma unroll
    for (int t = 1; t < 16; ++t) m = fmaxf(m, red[tid][t]);
    tmax[tid] = m;
  }
  __syncthreads();
#pragma unroll
  for (int u = 0; u < 8; ++u) {
    float m = tmax[ty * 8 + u], s = 0.f;
#pragma unroll
    for (int v = 0; v < 8; ++v) s += expf(acc[u][v] - m);
    red[ty * 8 + u][tx] = s;
  }
  __syncthreads();
  if (tid < 128) {
    float s = 0.f;
#pragma unroll
    for (int t = 0; t < 16; ++t) s += red[tid][t];
    rowpart[(size_t)(i0 + tid) * 64 + blockIdx.x] = make_float2(tmax[tid], s);
  }
  __syncthreads();
  // ---- col stats: valid rows only ----
#pragma unroll
  for (int v = 0; v < 8; ++v) {
    float m = -INFINITY;
#pragma unroll
    for (int u = 0; u < 8; ++u)
      if (vrow[ty * 8 + u]) m = fmaxf(m, acc[u][v]);
    red[tx * 8 + v][ty] = m;
  }
  __syncthreads();
  if (tid < 128) {
    float m = red[tid][0];
#pragma unroll
    for (int t = 1; t < 16; ++t) m = fmaxf(m, red[tid][t]);
    tmax[tid] = m;
  }
  __syncthreads();
#pragma unroll
  for (int v = 0; v < 8; ++v) {
    float m = tmax[tx * 8 + v], s = 0.f;
    if (m > -INFINITY) {
#pragma unroll
      for (int u = 0; u < 8; ++u)
        if (vrow[ty * 8 + u]) s += expf(acc[u][v] - m);
    }
    red[tx * 8 + v][ty] = s;
  }
  __syncthreads();
  if (tid < 128) {
    float s = 0.f;
#pragma unroll
    for (int t = 0; t < 16; ++t) s += red[tid][t];
    colpart[(size_t)(j0 + tid) * 32 + blockIdx.y] = make_float2(tmax[tid], s);
  }
}

// ---------- 4. fused merge stats + reciprocals ----------
__global__ __launch_bounds__(256) void k_merge(const float2* __restrict__ rowpart,
                                               const float2* __restrict__ colpart,
                                               float* rmax, float* rsinv,
                                               float* cmax, float* csinv) {
  int b = blockIdx.x;
  if (b < 16) {
    int r = b * 256 + threadIdx.x;
    float M = -INFINITY;
    for (int c = 0; c < 64; ++c) M = fmaxf(M, rowpart[(size_t)r * 64 + c].x);
    float s = 0.f;
    for (int c = 0; c < 64; ++c) {
      float2 p = rowpart[(size_t)r * 64 + c];
      s += p.y * expf(p.x - M);
    }
    rmax[r] = M;
    rsinv[r] = 1.0f / s;
  } else {
    int c = (b - 16) * 256 + threadIdx.x;
    float M = -INFINITY;
    for (int q = 0; q < 32; ++q) {
      float2 p = colpart[(size_t)c * 32 + q];
      if (p.y > 0.f) M = fmaxf(M, p.x);
    }
    float s = 0.f;
    for (int q = 0; q < 32; ++q) {
      float2 p = colpart[(size_t)c * 32 + q];
      if (p.y > 0.f) s += p.y * expf(p.x - M);
    }
    cmax[c] = M;
    csinv[c] = 1.0f / s;
  }
}

// ---------- 5. in-place transform feats -> sims (fp32) + candidates ----------
__global__ __launch_bounds__(256) void k_transform(float* __restrict__ sims,
                                                   const float* __restrict__ rmax,
                                                   const float* __restrict__ rsinv,
                                                   const float* __restrict__ cmax,
                                                   const float* __restrict__ csinv,
                                                   const int* __restrict__ scls,
                                                   const int* __restrict__ mcls,
                                                   const int* __restrict__ svalid,
                                                   float* __restrict__ cval,
                                                   int* __restrict__ cidx,
                                                   int* __restrict__ ccnt) {
  const int r = blockIdx.x, tid = threadIdx.x;
  float* row = sims + (size_t)r * NMEM;
  if (!svalid[r]) {
    float4 z = {0.f, 0.f, 0.f, 0.f};
#pragma unroll
    for (int it = 0; it < 8; ++it) *(float4*)(row + it * 1024 + tid * 4) = z;
    return;
  }
  const float rm = rmax[r], rsi = rsinv[r];
  const int rc = scls[r];
#pragma unroll
  for (int it = 0; it < 8; ++it) {
    int j = it * 1024 + tid * 4;
    float4 f = *(const float4*)(row + j);
    float4 cm4 = *(const float4*)(cmax + j);
    float4 cs4 = *(const float4*)(csinv + j);
    int4 mc4 = *(const int4*)(mcls + j);
    float4 o;
    o.x = sim_val(f.x, rm, rsi, cm4.x, cs4.x, rc == mc4.x);
    o.y = sim_val(f.y, rm, rsi, cm4.y, cs4.y, rc == mc4.y);
    o.z = sim_val(f.z, rm, rsi, cm4.z, cs4.z, rc == mc4.z);
    o.w = sim_val(f.w, rm, rsi, cm4.w, cs4.w, rc == mc4.w);
    *(float4*)(row + j) = o;
    float vs[4] = {o.x, o.y, o.z, o.w};
#pragma unroll
    for (int q = 0; q < 4; ++q) {
      if (vs[q] > 0.5f) {
        int ps = atomicAdd(&ccnt[r], 1);
        if (ps < CAP) {
          cval[(size_t)r * CAP + ps] = vs[q];
          cidx[(size_t)r * CAP + ps] = j + q;
        }
      }
    }
  }
}

// ---------- 6. greedy matching: scoped parallel + wave-cooperative serial ----
__global__ __launch_bounds__(256) void k_match(
    const float* __restrict__ cval, const int* __restrict__ cidx,
    const int* __restrict__ ccnt, const float* __restrict__ sscore,
    const int* __restrict__ svalid, const int* __restrict__ order,
    const int* __restrict__ mtrack, const int* __restrict__ ntptr,
    const float* __restrict__ sims, float* __restrict__ out) {
  const int tid = threadIdx.x;
  __shared__ float pv[POOL];
  __shared__ unsigned short pi[POOL];
  __shared__ int claim[NMEM];
  __shared__ int mt[NMEM];
  __shared__ int ids_s[NDET];
  __shared__ unsigned int taken[NMEM / 32];
  __shared__ int part[256];
  __shared__ float rv[256];
  __shared__ int ri[256];
  __shared__ unsigned short rlist[NDET];
  __shared__ unsigned short cstart[NDET];
  __shared__ unsigned char flags[NDET];
  __shared__ unsigned char cnt_s[NDET];
  __shared__ int nR_s, minOvf_s;

  if (tid == 0) minOvf_s = NDET;
  for (int r = tid; r < NDET; r += 256) {
    float s = sscore[r];
    int c = ccnt[r];
    flags[r] = (unsigned char)((svalid[r] ? 1 : 0) | (s > 0.3f ? 2 : 0) |
                               (s > 0.7f ? 4 : 0));
    cnt_s[r] = (unsigned char)(c > 255 ? 255 : c);
    ids_s[r] = -1;
  }
  for (int j = tid; j < NMEM; j += 256) {
    mt[j] = mtrack[j];
    claim[j] = 0;
  }
  taken[tid] = 0u;
  __syncthreads();

  const int base = tid * 16;
  int pool_need = 0;
  for (int k = 0; k < 16; ++k) {
    int c = cnt_s[base + k];
    pool_need += (c > 0 && c <= CAP) ? c : 0;
  }
  part[tid] = pool_need;
  __syncthreads();
  if (tid == 0) {
    int run = 0;
    for (int t = 0; t < 256; ++t) { int v = part[t]; part[t] = run; run += v; }
  }
  __syncthreads();
  {
    int off = part[tid];
    for (int k = 0; k < 16; ++k) {
      int r = base + k;
      int c = cnt_s[r];
      if (c == 0) continue;
      if (c > CAP) {
        atomicMin(&minOvf_s, r);
        cstart[r] = 0xFFFFu;
        continue;
      }
      unsigned short st = (off + c <= POOL) ? (unsigned short)off : (unsigned short)0xFFFFu;
      cstart[r] = st;
      for (int q = 0; q < c; ++q) {
        int j = cidx[(size_t)r * CAP + q];
        atomicAdd(&claim[j], 1);
        if (st != 0xFFFFu) {
          pv[off + q] = cval[(size_t)r * CAP + q];
          pi[off + q] = (unsigned short)j;
        }
      }
      off += c;
    }
  }
  __syncthreads();
  const int minOvf = minOvf_s;

  for (int k = 0; k < 16; ++k) {
    int r = base + k;
    int c = cnt_s[r];
    if (c == 0 || c > CAP || r >= minOvf) continue;
    bool indep = true;
    float bvv = -1.f;
    int bii = 1 << 30;
    const unsigned st = cstart[r];
    for (int q = 0; q < c; ++q) {
      int j;
      float v;
      if (st != 0xFFFFu) { j = pi[st + q]; v = pv[st + q]; }
      else { j = cidx[(size_t)r * CAP + q]; v = cval[(size_t)r * CAP + q]; }
      if (claim[j] != 1) indep = false;
      if (v > bvv || (v == bvv && j < bii)) { bvv = v; bii = j; }
    }
    if (indep) {
      int cur = mt[bii];
      if (cur > -1) {
        if (flags[r] & 2) {
          ids_s[r] = cur;
          atomicOr(&taken[bii >> 5], 1u << (bii & 31));
        }
      } else ids_s[r] = -2;
      cnt_s[r] = 0;
    }
  }
  __syncthreads();

  int cn = 0;
  for (int k = 0; k < 16; ++k) cn += (cnt_s[base + k] > 0);
  part[tid] = cn;
  __syncthreads();
  if (tid == 0) {
    int run = 0;
    for (int t = 0; t < 256; ++t) { int v = part[t]; part[t] = run; run += v; }
    nR_s = run;
  }
  __syncthreads();
  {
    int pos = part[tid];
    for (int k = 0; k < 16; ++k)
      if (cnt_s[base + k] > 0) rlist[pos++] = (unsigned short)(base + k);
  }
  __syncthreads();
  const int nR = nR_s;

  for (int t = 0; t < nR; ++t) {
    const int r = rlist[t];
    const int c = cnt_s[r];
    if (c <= CAP) {
      if (tid < 64) {
        const unsigned st = cstart[r];
        float v = -1.f;
        int jj = 0x7fffffff;
        if (tid < c) {
          int j;
          float vv;
          if (st != 0xFFFFu) { j = pi[st + tid]; vv = pv[st + tid]; }
          else { j = cidx[(size_t)r * CAP + tid]; vv = cval[(size_t)r * CAP + tid]; }
          if (!((taken[j >> 5] >> (j & 31)) & 1u)) { v = vv; jj = j; }
        }
#pragma unroll
        for (int off = 32; off > 0; off >>= 1) {
          float v2 = __shfl_xor(v, off);
          int j2 = __shfl_xor(jj, off);
          if (v2 > v || (v2 == v && j2 < jj)) { v = v2; jj = j2; }
        }
        if (tid == 0 && v > 0.5f) {
          int cur = mt[jj];
          if (cur > -1) {
            if (flags[r] & 2) { ids_s[r] = cur; taken[jj >> 5] |= 1u << (jj & 31); }
          } else ids_s[r] = -2;
        }
      }
      __threadfence_block();
    } else {
      __syncthreads();
      const float* srow = sims + (size_t)r * NMEM;
      float bvv = -1.f;
      int bii = 1 << 30;
      for (int j = tid; j < NMEM; j += 256) {
        float v = ((taken[j >> 5] >> (j & 31)) & 1u) ? 0.f : srow[j];
        if (v > bvv || (v == bvv && j < bii)) { bvv = v; bii = j; }
      }
      rv[tid] = bvv;
      ri[tid] = bii;
      __syncthreads();
      for (int off = 128; off > 0; off >>= 1) {
        if (tid < off) {
          float v2 = rv[tid + off];
          int i2 = ri[tid + off];
          if (v2 > rv[tid] || (v2 == rv[tid] && i2 < ri[tid])) { rv[tid] = v2; ri[tid] = i2; }
        }
        __syncthreads();
      }
      if (tid == 0) {
        float conf = rv[0];
        int ind = ri[0];
        if (conf > 0.5f) {
          int cur = mt[ind];
          if (cur > -1) {
            if (flags[r] & 2) { ids_s[r] = cur; taken[ind >> 5] |= 1u << (ind & 31); }
          } else ids_s[r] = -2;
        }
      }
      __syncthreads();
    }
  }
  __syncthreads();

  int cntNew = 0;
  for (int k = 0; k < 16; ++k) {
    int r = base + k;
    cntNew += (ids_s[r] == -1 && (flags[r] & 4) && (flags[r] & 1));
  }
  part[tid] = cntNew;
  __syncthreads();
  if (tid == 0) {
    int run = 0;
    for (int t2 = 0; t2 < 256; ++t2) { int v = part[t2]; part[t2] = run; run += v; }
  }
  __syncthreads();
  const int nt = ntptr[0];
  int off2 = part[tid];
  for (int k = 0; k < 16; ++k) {
    int r = base + k;
    if (ids_s[r] == -1 && (flags[r] & 4) && (flags[r] & 1)) ids_s[r] = nt + off2++;
  }
  __syncthreads();
  for (int r = tid; r < NDET; r += 256) {
    int o = order[r];
    out[o] = (float)ids_s[r];
    out[NDET + o] = (flags[r] & 1) ? 1.0f : 0.0f;
  }
}

extern "C" void kernel_launch(void* const* d_in, const int* in_sizes, int n_in,
                              void* d_out, int out_size, void* d_ws, size_t ws_size,
                              hipStream_t stream) {
  const float* det = (const float*)d_in[0];
  const float* scores = (const float*)d_in[1];
  const int* cls = (const int*)d_in[2];
  const float* emb = (const float*)d_in[3];
  const float* memo = (const float*)d_in[4];
  const int* mcls = (const int*)d_in[5];
  const int* mtrack = (const int*)d_in[6];
  const int* ntptr = (const int*)d_in[7];
  float* out = (float*)d_out;     // fp32 outputs: [ids | valid | sims]
  float* feats = out + 2 * NDET;  // sims region doubles as feats scratch

  char* ws = (char*)d_ws;
  size_t o_A = 0;                                        // 4 MB
  size_t o_order = o_A + (size_t)NDET * DEMB * 4;
  size_t o_sscore = o_order + NDET * 4;
  size_t o_scls = o_sscore + NDET * 4;
  size_t o_svalid = o_scls + NDET * 4;
  size_t o_sbox = o_svalid + NDET * 4;
  size_t o_rowpart = o_sbox + NDET * 16;                 // 2 MB
  size_t o_colpart = o_rowpart + (size_t)NDET * 64 * 8;  // 2 MB
  size_t o_rmax = o_colpart + (size_t)NMEM * 32 * 8;
  size_t o_rsinv = o_rmax + NDET * 4;
  size_t o_cmax = o_rsinv + NDET * 4;
  size_t o_csinv = o_cmax + NMEM * 4;
  size_t o_cval = o_csinv + NMEM * 4;                    // 1 MB
  size_t o_cidx = o_cval + (size_t)NDET * CAP * 4;       // 1 MB
  size_t o_ccnt = o_cidx + (size_t)NDET * CAP * 4;       // 16 KB

  float* A = (float*)(ws + o_A);
  int* order = (int*)(ws + o_order);
  float* sscore = (float*)(ws + o_sscore);
  int* scls = (int*)(ws + o_scls);
  int* svalid = (int*)(ws + o_svalid);
  float* sbox = (float*)(ws + o_sbox);
  float2* rowpart = (float2*)(ws + o_rowpart);
  float2* colpart = (float2*)(ws + o_colpart);
  float* rmax = (float*)(ws + o_rmax);
  float* rsinv = (float*)(ws + o_rsinv);
  float* cmax = (float*)(ws + o_cmax);
  float* csinv = (float*)(ws + o_csinv);
  float* cval = (float*)(ws + o_cval);
  int* cidx = (int*)(ws + o_cidx);
  int* ccnt = (int*)(ws + o_ccnt);

  k_prep<<<NDET / 256, 256, 0, stream>>>(scores, cls, det, emb, order, sscore, scls,
                                         sbox, ccnt, A);
  k_valid<<<NDET, 256, 0, stream>>>(sbox, sscore, svalid);
  k_gemm1<<<dim3(NMEM / 128, NDET / 128), 256, 0, stream>>>(A, memo, svalid, rowpart,
                                                            colpart, feats);
  k_merge<<<48, 256, 0, stream>>>(rowpart, colpart, rmax, rsinv, cmax, csinv);
  k_transform<<<NDET, 256, 0, stream>>>(feats, rmax, rsinv, cmax, csinv, scls, mcls,
                                        svalid, cval, cidx, ccnt);
  k_match<<<1, 256, 0, stream>>>(cval, cidx, ccnt, sscore, svalid, order, mtrack,
                                 ntptr, feats, out);
}

// Round 9
// 601.093 us; speedup vs baseline: 1.8162x; 1.8162x over previous
//
#include <hip/hip_runtime.h>

#define NDET 4096
#define NMEM 8192
#define DEMB 256
#define CAP  64
#define POOL 6144
#define PM 260  // As pitch (k-major, m-dim 256 + 4) ; %4==0 keeps b128 aligned
#define PB 132  // Bs pitch (k-major, n-dim 128 + 4) ; %4==0

static __device__ __forceinline__ float sim_val(float f, float rm, float rsi,
                                                float cm, float csi, bool same) {
  if (!same) return 0.0f;
  return 0.5f * (expf(f - rm) * rsi + expf(f - cm) * csi);
}

// ---------- 1. fused: stable rank sort + ccnt zero + gather ----------
__global__ __launch_bounds__(256) void k_prep(const float* __restrict__ scores,
                                              const int* __restrict__ cls,
                                              const float* __restrict__ det,
                                              const float* __restrict__ emb,
                                              int* order, float* sscore, int* scls,
                                              float* sboxes, int* ccnt, float* A) {
  __shared__ float s[NDET];
  __shared__ int rank_s[256];
  int tid = threadIdx.x;
  for (int i = tid; i < NDET; i += 256) s[i] = scores[i];
  __syncthreads();
  int i = blockIdx.x * 256 + tid;
  ccnt[i] = 0;
  float si = s[i];
  int rank = 0;
  for (int j = 0; j < NDET; ++j) {
    float sj = s[j];
    rank += (sj > si) || (sj == si && j < i);
  }
  order[rank] = i;
  sscore[rank] = si;
  scls[rank] = cls[i];
  ((float4*)sboxes)[rank] = ((const float4*)det)[i];
  rank_s[tid] = rank;
  __syncthreads();
  int grp = tid >> 6, lane = tid & 63;
  for (int k = grp; k < 256; k += 4) {
    int src = blockIdx.x * 256 + k;
    int dst = rank_s[k];
    ((float4*)A)[(size_t)dst * 64 + lane] =
        ((const float4*)emb)[(size_t)src * 64 + lane];
  }
}

// ---------- 2. NMS validity (all j < i suppress, as in source) ----------
__global__ __launch_bounds__(256) void k_valid(const float* __restrict__ sbox,
                                               const float* __restrict__ sscore,
                                               int* svalid) {
  int i = blockIdx.x, tid = threadIdx.x;
  float4 bi = ((const float4*)sbox)[i];
  float thr = (sscore[i] < 0.3f) ? 0.3f : 0.7f;
  float ai = fmaxf(bi.z - bi.x, 0.f) * fmaxf(bi.w - bi.y, 0.f);
  __shared__ int flag;
  if (tid == 0) flag = 0;
  __syncthreads();
  int any = 0;
  for (int j = tid; j < i; j += 256) {
    float4 bj = ((const float4*)sbox)[j];
    float aj = fmaxf(bj.z - bj.x, 0.f) * fmaxf(bj.w - bj.y, 0.f);
    float lx = fmaxf(bi.x, bj.x), ly = fmaxf(bi.y, bj.y);
    float rx = fminf(bi.z, bj.z), ry = fminf(bi.w, bj.w);
    float w = fmaxf(rx - lx, 0.f), h = fmaxf(ry - ly, 0.f);
    float inter = w * h;
    float den = fmaxf(ai + aj - inter, 1e-6f);
    any |= ((inter / den) > thr);
  }
  if (any) atomicOr(&flag, 1);
  __syncthreads();
  if (tid == 0) svalid[i] = flag ? 0 : 1;
}

#define FMA8(U, AS)                                \
  acc[U][0] = __builtin_fmaf(AS, b0.x, acc[U][0]); \
  acc[U][1] = __builtin_fmaf(AS, b0.y, acc[U][1]); \
  acc[U][2] = __builtin_fmaf(AS, b0.z, acc[U][2]); \
  acc[U][3] = __builtin_fmaf(AS, b0.w, acc[U][3]); \
  acc[U][4] = __builtin_fmaf(AS, b1.x, acc[U][4]); \
  acc[U][5] = __builtin_fmaf(AS, b1.y, acc[U][5]); \
  acc[U][6] = __builtin_fmaf(AS, b1.z, acc[U][6]); \
  acc[U][7] = __builtin_fmaf(AS, b1.w, acc[U][7]);

// ---------- 3. GEMM: 256x128 block tile, 16x8 per-thread tile ----------
// LDS reads/kk = 6 b128 for 128 FMAs (ratio 1.125 vs 1.5 at 8x8).
__global__ __launch_bounds__(256, 2) void k_gemm1(const float* __restrict__ A,
                                                  const float* __restrict__ B,
                                                  const int* __restrict__ svalid,
                                                  float2* __restrict__ rowpart,
                                                  float2* __restrict__ colpart,
                                                  float* __restrict__ feats) {
  __shared__ float smraw[32 * PM + 32 * PB];  // 50176 B
  float (*As)[PM] = (float (*)[PM])smraw;
  float (*Bs)[PB] = (float (*)[PB])(smraw + 32 * PM);
  float (*redr)[17] = (float (*)[17])smraw;  // epilogue alias [256][17]
  float* tmaxr = smraw + 256 * 17;
  float (*redc)[17] = (float (*)[17])smraw;  // epilogue alias [128][17]
  float* tmaxc = smraw + 128 * 17;
  __shared__ unsigned char vrow[256];
  const int tid = threadIdx.x;
  const int tx = tid & 15, ty = tid >> 4;
  const int j0 = blockIdx.x * 128, i0 = blockIdx.y * 256;
  vrow[tid] = (unsigned char)svalid[i0 + tid];
  float acc[16][8];
#pragma unroll
  for (int u = 0; u < 16; ++u)
#pragma unroll
    for (int v = 0; v < 8; ++v) acc[u][v] = 0.f;

  for (int kt = 0; kt < DEMB / 32; ++kt) {
    const int k0 = kt * 32;
    float4 av[8], bv[4];
#pragma unroll
    for (int e = 0; e < 8; ++e) {
      int f = e * 256 + tid;
      av[e] = *(const float4*)(A + (size_t)(i0 + (f >> 3)) * DEMB + k0 + ((f & 7) << 2));
    }
#pragma unroll
    for (int e = 0; e < 4; ++e) {
      int f = e * 256 + tid;
      bv[e] = *(const float4*)(B + (size_t)(j0 + (f >> 3)) * DEMB + k0 + ((f & 7) << 2));
    }
    __syncthreads();
#pragma unroll
    for (int e = 0; e < 8; ++e) {
      int f = e * 256 + tid;
      int rr = f >> 3, cc = (f & 7) << 2;
      As[cc + 0][rr] = av[e].x;
      As[cc + 1][rr] = av[e].y;
      As[cc + 2][rr] = av[e].z;
      As[cc + 3][rr] = av[e].w;
    }
#pragma unroll
    for (int e = 0; e < 4; ++e) {
      int f = e * 256 + tid;
      int rr = f >> 3, cc = (f & 7) << 2;
      Bs[cc + 0][rr] = bv[e].x;
      Bs[cc + 1][rr] = bv[e].y;
      Bs[cc + 2][rr] = bv[e].z;
      Bs[cc + 3][rr] = bv[e].w;
    }
    __syncthreads();
#pragma unroll 4
    for (int kk = 0; kk < 32; ++kk) {
      float4 a0 = *(const float4*)&As[kk][ty * 16];
      float4 a1 = *(const float4*)&As[kk][ty * 16 + 4];
      float4 a2 = *(const float4*)&As[kk][ty * 16 + 8];
      float4 a3 = *(const float4*)&As[kk][ty * 16 + 12];
      float4 b0 = *(const float4*)&Bs[kk][tx * 8];
      float4 b1 = *(const float4*)&Bs[kk][tx * 8 + 4];
      FMA8(0, a0.x) FMA8(1, a0.y) FMA8(2, a0.z) FMA8(3, a0.w)
      FMA8(4, a1.x) FMA8(5, a1.y) FMA8(6, a1.z) FMA8(7, a1.w)
      FMA8(8, a2.x) FMA8(9, a2.y) FMA8(10, a2.z) FMA8(11, a2.w)
      FMA8(12, a3.x) FMA8(13, a3.y) FMA8(14, a3.z) FMA8(15, a3.w)
    }
  }
  // ---- store raw feats (fp32) into the sims output region ----
#pragma unroll
  for (int u = 0; u < 16; ++u) {
    int row = i0 + ty * 16 + u;
    float4 o0 = {acc[u][0], acc[u][1], acc[u][2], acc[u][3]};
    float4 o1 = {acc[u][4], acc[u][5], acc[u][6], acc[u][7]};
    *(float4*)(feats + (size_t)row * NMEM + j0 + tx * 8) = o0;
    *(float4*)(feats + (size_t)row * NMEM + j0 + tx * 8 + 4) = o1;
  }
  __syncthreads();  // K-loop LDS dead; epilogue aliases it
  // ---- row stats: exact max-then-sum within tile ----
#pragma unroll
  for (int u = 0; u < 16; ++u) {
    float m = acc[u][0];
#pragma unroll
    for (int v = 1; v < 8; ++v) m = fmaxf(m, acc[u][v]);
    redr[ty * 16 + u][tx] = m;
  }
  __syncthreads();
  {
    float m = redr[tid][0];
#pragma unroll
    for (int t = 1; t < 16; ++t) m = fmaxf(m, redr[tid][t]);
    tmaxr[tid] = m;
  }
  __syncthreads();
#pragma unroll
  for (int u = 0; u < 16; ++u) {
    float m = tmaxr[ty * 16 + u], s = 0.f;
#pragma unroll
    for (int v = 0; v < 8; ++v) s += expf(acc[u][v] - m);
    redr[ty * 16 + u][tx] = s;
  }
  __syncthreads();
  {
    float s = 0.f;
#pragma unroll
    for (int t = 0; t < 16; ++t) s += redr[tid][t];
    rowpart[(size_t)(i0 + tid) * 64 + blockIdx.x] = make_float2(tmaxr[tid], s);
  }
  __syncthreads();
  // ---- col stats: valid rows only ----
#pragma unroll
  for (int v = 0; v < 8; ++v) {
    float m = -INFINITY;
#pragma unroll
    for (int u = 0; u < 16; ++u)
      if (vrow[ty * 16 + u]) m = fmaxf(m, acc[u][v]);
    redc[tx * 8 + v][ty] = m;
  }
  __syncthreads();
  if (tid < 128) {
    float m = redc[tid][0];
#pragma unroll
    for (int t = 1; t < 16; ++t) m = fmaxf(m, redc[tid][t]);
    tmaxc[tid] = m;
  }
  __syncthreads();
#pragma unroll
  for (int v = 0; v < 8; ++v) {
    float m = tmaxc[tx * 8 + v], s = 0.f;
    if (m > -INFINITY) {
#pragma unroll
      for (int u = 0; u < 16; ++u)
        if (vrow[ty * 16 + u]) s += expf(acc[u][v] - m);
    }
    redc[tx * 8 + v][ty] = s;
  }
  __syncthreads();
  if (tid < 128) {
    float s = 0.f;
#pragma unroll
    for (int t = 0; t < 16; ++t) s += redc[tid][t];
    colpart[(size_t)(j0 + tid) * 16 + blockIdx.y] = make_float2(tmaxc[tid], s);
  }
}

// ---------- 4. fused merge stats + reciprocals ----------
__global__ __launch_bounds__(256) void k_merge(const float2* __restrict__ rowpart,
                                               const float2* __restrict__ colpart,
                                               float* rmax, float* rsinv,
                                               float* cmax, float* csinv) {
  int b = blockIdx.x;
  if (b < 16) {
    int r = b * 256 + threadIdx.x;
    float M = -INFINITY;
    for (int c = 0; c < 64; ++c) M = fmaxf(M, rowpart[(size_t)r * 64 + c].x);
    float s = 0.f;
    for (int c = 0; c < 64; ++c) {
      float2 p = rowpart[(size_t)r * 64 + c];
      s += p.y * expf(p.x - M);
    }
    rmax[r] = M;
    rsinv[r] = 1.0f / s;
  } else {
    int c = (b - 16) * 256 + threadIdx.x;
    float M = -INFINITY;
    for (int q = 0; q < 16; ++q) {
      float2 p = colpart[(size_t)c * 16 + q];
      if (p.y > 0.f) M = fmaxf(M, p.x);
    }
    float s = 0.f;
    for (int q = 0; q < 16; ++q) {
      float2 p = colpart[(size_t)c * 16 + q];
      if (p.y > 0.f) s += p.y * expf(p.x - M);
    }
    cmax[c] = M;
    csinv[c] = 1.0f / s;
  }
}

// ---------- 5. in-place transform feats -> sims (fp32) + candidates ----------
__global__ __launch_bounds__(256) void k_transform(float* __restrict__ sims,
                                                   const float* __restrict__ rmax,
                                                   const float* __restrict__ rsinv,
                                                   const float* __restrict__ cmax,
                                                   const float* __restrict__ csinv,
                                                   const int* __restrict__ scls,
                                                   const int* __restrict__ mcls,
                                                   const int* __restrict__ svalid,
                                                   float* __restrict__ cval,
                                                   int* __restrict__ cidx,
                                                   int* __restrict__ ccnt) {
  const int r = blockIdx.x, tid = threadIdx.x;
  float* row = sims + (size_t)r * NMEM;
  if (!svalid[r]) {
    float4 z = {0.f, 0.f, 0.f, 0.f};
#pragma unroll
    for (int it = 0; it < 8; ++it) *(float4*)(row + it * 1024 + tid * 4) = z;
    return;
  }
  const float rm = rmax[r], rsi = rsinv[r];
  const int rc = scls[r];
#pragma unroll
  for (int it = 0; it < 8; ++it) {
    int j = it * 1024 + tid * 4;
    float4 f = *(const float4*)(row + j);
    float4 cm4 = *(const float4*)(cmax + j);
    float4 cs4 = *(const float4*)(csinv + j);
    int4 mc4 = *(const int4*)(mcls + j);
    float4 o;
    o.x = sim_val(f.x, rm, rsi, cm4.x, cs4.x, rc == mc4.x);
    o.y = sim_val(f.y, rm, rsi, cm4.y, cs4.y, rc == mc4.y);
    o.z = sim_val(f.z, rm, rsi, cm4.z, cs4.z, rc == mc4.z);
    o.w = sim_val(f.w, rm, rsi, cm4.w, cs4.w, rc == mc4.w);
    *(float4*)(row + j) = o;
    float vs[4] = {o.x, o.y, o.z, o.w};
#pragma unroll
    for (int q = 0; q < 4; ++q) {
      if (vs[q] > 0.5f) {
        int ps = atomicAdd(&ccnt[r], 1);
        if (ps < CAP) {
          cval[(size_t)r * CAP + ps] = vs[q];
          cidx[(size_t)r * CAP + ps] = j + q;
        }
      }
    }
  }
}

// ---------- 6. greedy matching: scoped parallel + wave-cooperative serial ----
__global__ __launch_bounds__(256) void k_match(
    const float* __restrict__ cval, const int* __restrict__ cidx,
    const int* __restrict__ ccnt, const float* __restrict__ sscore,
    const int* __restrict__ svalid, const int* __restrict__ order,
    const int* __restrict__ mtrack, const int* __restrict__ ntptr,
    const float* __restrict__ sims, float* __restrict__ out) {
  const int tid = threadIdx.x;
  __shared__ float pv[POOL];
  __shared__ unsigned short pi[POOL];
  __shared__ int claim[NMEM];
  __shared__ int mt[NMEM];
  __shared__ int ids_s[NDET];
  __shared__ unsigned int taken[NMEM / 32];
  __shared__ int part[256];
  __shared__ float rv[256];
  __shared__ int ri[256];
  __shared__ unsigned short rlist[NDET];
  __shared__ unsigned short cstart[NDET];
  __shared__ unsigned char flags[NDET];
  __shared__ unsigned char cnt_s[NDET];
  __shared__ int nR_s, minOvf_s;

  if (tid == 0) minOvf_s = NDET;
  for (int r = tid; r < NDET; r += 256) {
    float s = sscore[r];
    int c = ccnt[r];
    flags[r] = (unsigned char)((svalid[r] ? 1 : 0) | (s > 0.3f ? 2 : 0) |
                               (s > 0.7f ? 4 : 0));
    cnt_s[r] = (unsigned char)(c > 255 ? 255 : c);
    ids_s[r] = -1;
  }
  for (int j = tid; j < NMEM; j += 256) {
    mt[j] = mtrack[j];
    claim[j] = 0;
  }
  taken[tid] = 0u;
  __syncthreads();

  const int base = tid * 16;
  int pool_need = 0;
  for (int k = 0; k < 16; ++k) {
    int c = cnt_s[base + k];
    pool_need += (c > 0 && c <= CAP) ? c : 0;
  }
  part[tid] = pool_need;
  __syncthreads();
  if (tid == 0) {
    int run = 0;
    for (int t = 0; t < 256; ++t) { int v = part[t]; part[t] = run; run += v; }
  }
  __syncthreads();
  {
    int off = part[tid];
    for (int k = 0; k < 16; ++k) {
      int r = base + k;
      int c = cnt_s[r];
      if (c == 0) continue;
      if (c > CAP) {
        atomicMin(&minOvf_s, r);
        cstart[r] = 0xFFFFu;
        continue;
      }
      unsigned short st = (off + c <= POOL) ? (unsigned short)off : (unsigned short)0xFFFFu;
      cstart[r] = st;
      for (int q = 0; q < c; ++q) {
        int j = cidx[(size_t)r * CAP + q];
        atomicAdd(&claim[j], 1);
        if (st != 0xFFFFu) {
          pv[off + q] = cval[(size_t)r * CAP + q];
          pi[off + q] = (unsigned short)j;
        }
      }
      off += c;
    }
  }
  __syncthreads();
  const int minOvf = minOvf_s;

  for (int k = 0; k < 16; ++k) {
    int r = base + k;
    int c = cnt_s[r];
    if (c == 0 || c > CAP || r >= minOvf) continue;
    bool indep = true;
    float bvv = -1.f;
    int bii = 1 << 30;
    const unsigned st = cstart[r];
    for (int q = 0; q < c; ++q) {
      int j;
      float v;
      if (st != 0xFFFFu) { j = pi[st + q]; v = pv[st + q]; }
      else { j = cidx[(size_t)r * CAP + q]; v = cval[(size_t)r * CAP + q]; }
      if (claim[j] != 1) indep = false;
      if (v > bvv || (v == bvv && j < bii)) { bvv = v; bii = j; }
    }
    if (indep) {
      int cur = mt[bii];
      if (cur > -1) {
        if (flags[r] & 2) {
          ids_s[r] = cur;
          atomicOr(&taken[bii >> 5], 1u << (bii & 31));
        }
      } else ids_s[r] = -2;
      cnt_s[r] = 0;
    }
  }
  __syncthreads();

  int cn = 0;
  for (int k = 0; k < 16; ++k) cn += (cnt_s[base + k] > 0);
  part[tid] = cn;
  __syncthreads();
  if (tid == 0) {
    int run = 0;
    for (int t = 0; t < 256; ++t) { int v = part[t]; part[t] = run; run += v; }
    nR_s = run;
  }
  __syncthreads();
  {
    int pos = part[tid];
    for (int k = 0; k < 16; ++k)
      if (cnt_s[base + k] > 0) rlist[pos++] = (unsigned short)(base + k);
  }
  __syncthreads();
  const int nR = nR_s;

  for (int t = 0; t < nR; ++t) {
    const int r = rlist[t];
    const int c = cnt_s[r];
    if (c <= CAP) {
      if (tid < 64) {
        const unsigned st = cstart[r];
        float v = -1.f;
        int jj = 0x7fffffff;
        if (tid < c) {
          int j;
          float vv;
          if (st != 0xFFFFu) { j = pi[st + tid]; vv = pv[st + tid]; }
          else { j = cidx[(size_t)r * CAP + tid]; vv = cval[(size_t)r * CAP + tid]; }
          if (!((taken[j >> 5] >> (j & 31)) & 1u)) { v = vv; jj = j; }
        }
#pragma unroll
        for (int off = 32; off > 0; off >>= 1) {
          float v2 = __shfl_xor(v, off);
          int j2 = __shfl_xor(jj, off);
          if (v2 > v || (v2 == v && j2 < jj)) { v = v2; jj = j2; }
        }
        if (tid == 0 && v > 0.5f) {
          int cur = mt[jj];
          if (cur > -1) {
            if (flags[r] & 2) { ids_s[r] = cur; taken[jj >> 5] |= 1u << (jj & 31); }
          } else ids_s[r] = -2;
        }
      }
      __threadfence_block();
    } else {
      __syncthreads();
      const float* srow = sims + (size_t)r * NMEM;
      float bvv = -1.f;
      int bii = 1 << 30;
      for (int j = tid; j < NMEM; j += 256) {
        float v = ((taken[j >> 5] >> (j & 31)) & 1u) ? 0.f : srow[j];
        if (v > bvv || (v == bvv && j < bii)) { bvv = v; bii = j; }
      }
      rv[tid] = bvv;
      ri[tid] = bii;
      __syncthreads();
      for (int off = 128; off > 0; off >>= 1) {
        if (tid < off) {
          float v2 = rv[tid + off];
          int i2 = ri[tid + off];
          if (v2 > rv[tid] || (v2 == rv[tid] && i2 < ri[tid])) { rv[tid] = v2; ri[tid] = i2; }
        }
        __syncthreads();
      }
      if (tid == 0) {
        float conf = rv[0];
        int ind = ri[0];
        if (conf > 0.5f) {
          int cur = mt[ind];
          if (cur > -1) {
            if (flags[r] & 2) { ids_s[r] = cur; taken[ind >> 5] |= 1u << (ind & 31); }
          } else ids_s[r] = -2;
        }
      }
      __syncthreads();
    }
  }
  __syncthreads();

  int cntNew = 0;
  for (int k = 0; k < 16; ++k) {
    int r = base + k;
    cntNew += (ids_s[r] == -1 && (flags[r] & 4) && (flags[r] & 1));
  }
  part[tid] = cntNew;
  __syncthreads();
  if (tid == 0) {
    int run = 0;
    for (int t2 = 0; t2 < 256; ++t2) { int v = part[t2]; part[t2] = run; run += v; }
  }
  __syncthreads();
  const int nt = ntptr[0];
  int off2 = part[tid];
  for (int k = 0; k < 16; ++k) {
    int r = base + k;
    if (ids_s[r] == -1 && (flags[r] & 4) && (flags[r] & 1)) ids_s[r] = nt + off2++;
  }
  __syncthreads();
  for (int r = tid; r < NDET; r += 256) {
    int o = order[r];
    out[o] = (float)ids_s[r];
    out[NDET + o] = (flags[r] & 1) ? 1.0f : 0.0f;
  }
}

extern "C" void kernel_launch(void* const* d_in, const int* in_sizes, int n_in,
                              void* d_out, int out_size, void* d_ws, size_t ws_size,
                              hipStream_t stream) {
  const float* det = (const float*)d_in[0];
  const float* scores = (const float*)d_in[1];
  const int* cls = (const int*)d_in[2];
  const float* emb = (const float*)d_in[3];
  const float* memo = (const float*)d_in[4];
  const int* mcls = (const int*)d_in[5];
  const int* mtrack = (const int*)d_in[6];
  const int* ntptr = (const int*)d_in[7];
  float* out = (float*)d_out;     // fp32 outputs: [ids | valid | sims]
  float* feats = out + 2 * NDET;  // sims region doubles as feats scratch

  char* ws = (char*)d_ws;
  size_t o_A = 0;                                        // 4 MB
  size_t o_order = o_A + (size_t)NDET * DEMB * 4;
  size_t o_sscore = o_order + NDET * 4;
  size_t o_scls = o_sscore + NDET * 4;
  size_t o_svalid = o_scls + NDET * 4;
  size_t o_sbox = o_svalid + NDET * 4;
  size_t o_rowpart = o_sbox + NDET * 16;                 // 2 MB
  size_t o_colpart = o_rowpart + (size_t)NDET * 64 * 8;  // 1 MB
  size_t o_rmax = o_colpart + (size_t)NMEM * 16 * 8;
  size_t o_rsinv = o_rmax + NDET * 4;
  size_t o_cmax = o_rsinv + NDET * 4;
  size_t o_csinv = o_cmax + NMEM * 4;
  size_t o_cval = o_csinv + NMEM * 4;                    // 1 MB
  size_t o_cidx = o_cval + (size_t)NDET * CAP * 4;       // 1 MB
  size_t o_ccnt = o_cidx + (size_t)NDET * CAP * 4;       // 16 KB

  float* A = (float*)(ws + o_A);
  int* order = (int*)(ws + o_order);
  float* sscore = (float*)(ws + o_sscore);
  int* scls = (int*)(ws + o_scls);
  int* svalid = (int*)(ws + o_svalid);
  float* sbox = (float*)(ws + o_sbox);
  float2* rowpart = (float2*)(ws + o_rowpart);
  float2* colpart = (float2*)(ws + o_colpart);
  float* rmax = (float*)(ws + o_rmax);
  float* rsinv = (float*)(ws + o_rsinv);
  float* cmax = (float*)(ws + o_cmax);
  float* csinv = (float*)(ws + o_csinv);
  float* cval = (float*)(ws + o_cval);
  int* cidx = (int*)(ws + o_cidx);
  int* ccnt = (int*)(ws + o_ccnt);

  k_prep<<<NDET / 256, 256, 0, stream>>>(scores, cls, det, emb, order, sscore, scls,
                                         sbox, ccnt, A);
  k_valid<<<NDET, 256, 0, stream>>>(sbox, sscore, svalid);
  k_gemm1<<<dim3(NMEM / 128, NDET / 256), 256, 0, stream>>>(A, memo, svalid, rowpart,
                                                            colpart, feats);
  k_merge<<<48, 256, 0, stream>>>(rowpart, colpart, rmax, rsinv, cmax, csinv);
  k_transform<<<NDET, 256, 0, stream>>>(feats, rmax, rsinv, cmax, csinv, scls, mcls,
                                        svalid, cval, cidx, ccnt);
  k_match<<<1, 256, 0, stream>>>(cval, cidx, ccnt, sscore, svalid, order, mtrack,
                                 ntptr, feats, out);
}